// Round 5
// baseline (13534.007 us; speedup 1.0000x reference)
//
#include <hip/hip_runtime.h>
#include <hip/hip_fp16.h>

typedef float f32x4 __attribute__((ext_vector_type(4)));
typedef _Float16 f16x8 __attribute__((ext_vector_type(8)));
typedef _Float16 f16x4 __attribute__((ext_vector_type(4)));

// ---------------- LDS byte map (single-f16 activations) ----------------
// phase A: XP  [0,25872)  x staged f16 [49 pix][264 ch slots *2B] (stride 528)
//          XF  [25872,38808) conv0 out [49][132 ch slots] (stride 264)
//          XF2 [0,12936)  conv1 out (x_feat), aliases XP after conv0 done
// phase B: PL  [0,12936)  planes [49][132]: h0 ch0..63 (byte+0..127),
//                                           h1 ch64..127 (byte+128..255)
// FCP fc partials [4 waves][64] f32 @38816 ; PRD 2 ints @39840
// Z512: zeros @39872 (never written after init) — OOW fallback target
#define XP    0
#define XF    25872
#define XF2   0
#define PL    0
#define FCP   38816
#define PRD   39840
#define Z512  39872
#define LDSB  40384

__device__ __forceinline__ float sigmoidf_(float v) { return 1.0f / (1.0f + expf(-v)); }

// shifted-window conv GEMM, weights hi/lo f16 (A), acts single f16 (B):
// acc += Al*B + Ah*B  (exact in weights; act error = f16 input quantization)
template <int NKC, int NMI>
__device__ __forceinline__ void conv_mfma_run(
    const char* __restrict__ SHb, int baseB, int pstr2,
    const int (&kofs)[NKC], int q16,
    const _Float16* __restrict__ ghi, const _Float16* __restrict__ glo,
    int NMF, int miBase, int miStep,
    const int (&okc)[4], const int (&py0)[4], const int (&px0)[4],
    f32x4 (&acc)[NMI][4], int lane)
{
    for (int dy = -1; dy <= 1; ++dy)
    for (int dx = -1; dx <= 1; ++dx) {
        const int tap = (dy + 1) * 3 + (dx + 1);
        int bb[4];
        #pragma unroll
        for (int n = 0; n < 4; ++n) {
            int py = py0[n] + dy, px = px0[n] + dx;
            bool ok = okc[n] && ((unsigned)py < 7u) && ((unsigned)px < 7u);
            bb[n] = ok ? baseB + (py * 7 + px) * pstr2 : Z512;  // Z512+kof<=Z512+496: in zeros
        }
        #pragma unroll
        for (int kc = 0; kc < NKC; ++kc) {
            const int kof = kofs[kc] + q16;
            f16x8 B[4];
            #pragma unroll
            for (int n = 0; n < 4; ++n) B[n] = *(const f16x8*)(SHb + bb[n] + kof);
            #pragma unroll
            for (int ii = 0; ii < NMI; ++ii) {
                int frag = (((tap * NKC + kc) * NMF + (miBase + ii * miStep)) << 9) + lane * 8;
                f16x8 Ah = *(const f16x8*)(ghi + frag);
                f16x8 Al = *(const f16x8*)(glo + frag);
                #pragma unroll
                for (int n = 0; n < 4; ++n) {
                    acc[ii][n] = __builtin_amdgcn_mfma_f32_16x16x32_f16(Al, B[n], acc[ii][n], 0, 0, 0);
                    acc[ii][n] = __builtin_amdgcn_mfma_f32_16x16x32_f16(Ah, B[n], acc[ii][n], 0, 0, 0);
                }
            }
        }
    }
}

// one-hot map conv contribution injected at acc-init (map one-hot at pixel pv)
__device__ __forceinline__ void inject_onehot(
    f32x4 (&acc)[4][4], const float* __restrict__ wv, int pv,
    const int (&okc)[4], const int (&py0)[4], const int (&px0)[4], int w, int q)
{
    if (pv >= 49) return;                 // EOS / empty map
    int vy = pv / 7, vx = pv % 7;
    #pragma unroll
    for (int n = 0; n < 4; ++n) {
        int dy = vy - py0[n], dx = vx - px0[n];
        if (okc[n] && dy >= -1 && dy <= 1 && dx >= -1 && dx <= 1) {
            int tap = (dy + 1) * 3 + (dx + 1);
            const float* wp = wv + tap * 256 + w * 16 + q * 4;
            #pragma unroll
            for (int g = 0; g < 4; ++g)
                acc[g][n] += *(const f32x4*)(wp + g * 64);
        }
    }
}

extern "C" __global__ __launch_bounds__(256, 2)
void poly_fused(const float* __restrict__ x, const int* __restrict__ firstv,
                const float* __restrict__ b_c0, const float* __restrict__ b_c1,
                const float* __restrict__ cx0b, const float* __restrict__ ch0b,
                const float* __restrict__ cx1b, const float* __restrict__ ch1b,
                const float* __restrict__ fcb,
                const _Float16* __restrict__ c0hi, const _Float16* __restrict__ c0lo,
                const _Float16* __restrict__ c1hi, const _Float16* __restrict__ c1lo,
                const _Float16* __restrict__ cshi, const _Float16* __restrict__ cslo,
                const _Float16* __restrict__ g0hi, const _Float16* __restrict__ g0lo,
                const _Float16* __restrict__ g1hi, const _Float16* __restrict__ g1lo,
                const _Float16* __restrict__ fchi, const _Float16* __restrict__ fclo,
                const float* __restrict__ wv1,
                const float* __restrict__ wvp1, const float* __restrict__ wvp2,
                float* __restrict__ out)
{
    extern __shared__ char SHC[];
    float* SHf = (float*)SHC;
    const int tid = threadIdx.x, s = blockIdx.x;
    const int lane = tid & 63, w = tid >> 6;
    const int q = lane >> 4, l15 = lane & 15, q16 = q * 16;

    for (int i = tid; i < LDSB / 4; i += 256) SHf[i] = 0.f;
    __syncthreads();

    // per-lane column geometry (col = n*16 + l15; 49 live pixels)
    int okc[4], py0[4], px0[4];
    #pragma unroll
    for (int n = 0; n < 4; ++n) {
        int col = n * 16 + l15;
        okc[n] = col < 49;
        int p = okc[n] ? col : 0;
        py0[n] = p / 7; px0[n] = p % 7;
    }

    // ============ PHASE A ============
    const float* xs = x + (size_t)s * 12544;
    for (int e = tid; e < 12544; e += 256) {
        int ch = e / 49, p = e - ch * 49;
        *(_Float16*)(SHC + XP + p * 528 + ch * 2) = (_Float16)xs[e];
    }
    __syncthreads();                       // XP visible

    const int kofs8[8] = {0, 64, 128, 192, 256, 320, 384, 448};
    const int kofs4[4] = {0, 64, 128, 192};
    const int kofs2[2] = {0, 64};

    // conv0: M=128 (8 mfrags; wave owns w*2, w*2+1), K=256
    {
        f32x4 acc2[2][4];
        #pragma unroll
        for (int ii = 0; ii < 2; ++ii)
            #pragma unroll
            for (int n = 0; n < 4; ++n) acc2[ii][n] = (f32x4){0.f, 0.f, 0.f, 0.f};
        conv_mfma_run<8, 2>(SHC, XP, 528, kofs8, q16, c0hi, c0lo,
                            8, w * 2, 1, okc, py0, px0, acc2, lane);
        #pragma unroll
        for (int ii = 0; ii < 2; ++ii) {
            f32x4 bb = *(const f32x4*)(b_c0 + (w * 2 + ii) * 16 + q * 4);
            int chB = ((w * 2 + ii) * 16 + q * 4) * 2;
            #pragma unroll
            for (int n = 0; n < 4; ++n) if (okc[n]) {
                int p = n * 16 + l15;
                f16x4 h;
                #pragma unroll
                for (int r = 0; r < 4; ++r)
                    h[r] = (_Float16)fmaxf(acc2[ii][n][r] + bb[r], 0.f);
                *(f16x4*)(SHC + XF + p * 264 + chB) = h;
            }
        }
    }
    __syncthreads();                       // XF visible; XP reads all done

    // conv1: M=128, K=128, XF -> XF2 (aliases XP, safe now)
    {
        f32x4 acc2[2][4];
        #pragma unroll
        for (int ii = 0; ii < 2; ++ii)
            #pragma unroll
            for (int n = 0; n < 4; ++n) acc2[ii][n] = (f32x4){0.f, 0.f, 0.f, 0.f};
        conv_mfma_run<4, 2>(SHC, XF, 264, kofs4, q16, c1hi, c1lo,
                            8, w * 2, 1, okc, py0, px0, acc2, lane);
        #pragma unroll
        for (int ii = 0; ii < 2; ++ii) {
            f32x4 bb = *(const f32x4*)(b_c1 + (w * 2 + ii) * 16 + q * 4);
            int chB = ((w * 2 + ii) * 16 + q * 4) * 2;
            #pragma unroll
            for (int n = 0; n < 4; ++n) if (okc[n]) {
                int p = n * 16 + l15;
                f16x4 h;
                #pragma unroll
                for (int r = 0; r < 4; ++r)
                    h[r] = (_Float16)fmaxf(acc2[ii][n][r] + bb[r], 0.f);
                *(f16x4*)(SHC + XF2 + p * 264 + chB) = h;
            }
        }
    }
    __syncthreads();                       // XF2 visible

    // static gates st = conv_cs(x_feat) + (cx0b+ch0b) + v_first window
    f32x4 st[4][4];
    #pragma unroll
    for (int g = 0; g < 4; ++g)
        #pragma unroll
        for (int n = 0; n < 4; ++n) st[g][n] = (f32x4){0.f, 0.f, 0.f, 0.f};
    conv_mfma_run<4, 4>(SHC, XF2, 264, kofs4, q16, cshi, cslo,
                        16, w, 4, okc, py0, px0, st, lane);
    const int fv = firstv[s];
    {
        const int fy = fv / 7, fx = fv % 7;
        #pragma unroll
        for (int g = 0; g < 4; ++g) {
            int m0 = g * 64 + w * 16 + q * 4;
            f32x4 b0 = *(const f32x4*)(cx0b + m0);
            f32x4 bh = *(const f32x4*)(ch0b + m0);
            #pragma unroll
            for (int n = 0; n < 4; ++n) {
                st[g][n] += b0 + bh;
                int dy = fy - py0[n], dx = fx - px0[n];
                if (okc[n] && dy >= -1 && dy <= 1 && dx >= -1 && dx <= 1) {
                    int tap = (dy + 1) * 3 + (dx + 1);
                    st[g][n] += *(const f32x4*)(wv1 + tap * 256 + m0);
                }
            }
        }
    }
    __syncthreads();                       // cs reads of XF2 done

    // zero PL (aliases XF2) + init preds: vp1 = v_first, vp2 = empty(49)
    for (int i = tid; i < 12936 / 4; i += 256) SHf[i] = 0.f;
    if (tid == 0) { ((int*)(SHC + PRD))[0] = fv; ((int*)(SHC + PRD))[1] = 49; }
    __syncthreads();

    float c0s[4][4], c1s[4][4];
    #pragma unroll
    for (int n = 0; n < 4; ++n)
        #pragma unroll
        for (int r = 0; r < 4; ++r) { c0s[n][r] = 0.f; c1s[n][r] = 0.f; }

    float* outS = out + (size_t)s * 450;

    // ============ PHASE B: 9 recurrent steps ============
    for (int t = 0; t < 9; ++t) {
        f32x4 acc[4][4];
        // ---- L0 gates: acc = st + vp1/vp2 injections; conv over h0 (K=64) ----
        #pragma unroll
        for (int g = 0; g < 4; ++g)
            #pragma unroll
            for (int n = 0; n < 4; ++n) acc[g][n] = st[g][n];
        {
            int p1 = ((const int*)(SHC + PRD))[0];
            int p2 = ((const int*)(SHC + PRD))[1];
            inject_onehot(acc, wvp1, p1, okc, py0, px0, w, q);
            inject_onehot(acc, wvp2, p2, okc, py0, px0, w, q);
        }
        conv_mfma_run<2, 4>(SHC, PL, 264, kofs2, q16, g0hi, g0lo,
                            16, w, 4, okc, py0, px0, acc, lane);
        __syncthreads();                   // L0 reads of h0 done
        {   // L0 LSTM epilogue (in-lane), write h0 f16
            int chB = (w * 16 + q * 4) * 2;
            #pragma unroll
            for (int n = 0; n < 4; ++n) if (okc[n]) {
                int p = n * 16 + l15;
                f16x4 h;
                #pragma unroll
                for (int r = 0; r < 4; ++r) {
                    float ig = sigmoidf_(acc[0][n][r]);
                    float fg = sigmoidf_(acc[1][n][r]);
                    float gg = tanhf(acc[2][n][r]);
                    float og = sigmoidf_(acc[3][n][r]);
                    float cy = fg * c0s[n][r] + ig * gg;
                    c0s[n][r] = cy;
                    h[r] = (_Float16)(og * tanhf(cy));
                }
                *(f16x4*)(SHC + PL + p * 264 + chB) = h;
            }
        }
        __syncthreads();                   // h0 visible
        // ---- L1 gates: K = [h0 new | h1 old] = PL ch 0..127 ----
        #pragma unroll
        for (int g = 0; g < 4; ++g) {
            int m0 = g * 64 + w * 16 + q * 4;
            f32x4 b = *(const f32x4*)(cx1b + m0);
            b += *(const f32x4*)(ch1b + m0);
            #pragma unroll
            for (int n = 0; n < 4; ++n) acc[g][n] = b;
        }
        conv_mfma_run<4, 4>(SHC, PL, 264, kofs4, q16, g1hi, g1lo,
                            16, w, 4, okc, py0, px0, acc, lane);
        __syncthreads();                   // L1 reads of h1-old done
        {   // L1 LSTM epilogue, write h1 f16
            int chB = 128 + (w * 16 + q * 4) * 2;
            #pragma unroll
            for (int n = 0; n < 4; ++n) if (okc[n]) {
                int p = n * 16 + l15;
                f16x4 h;
                #pragma unroll
                for (int r = 0; r < 4; ++r) {
                    float ig = sigmoidf_(acc[0][n][r]);
                    float fg = sigmoidf_(acc[1][n][r]);
                    float gg = tanhf(acc[2][n][r]);
                    float og = sigmoidf_(acc[3][n][r]);
                    float cy = fg * c1s[n][r] + ig * gg;
                    c1s[n][r] = cy;
                    h[r] = (_Float16)(og * tanhf(cy));
                }
                *(f16x4*)(SHC + PL + p * 264 + chB) = h;
            }
        }
        __syncthreads();                   // h1 visible (fc input)
        {   // fc via MFMA: M=64 (50 live), K=3136 from PL h1; col 0 live
            f32x4 afc[4];
            #pragma unroll
            for (int mi = 0; mi < 4; ++mi) afc[mi] = (f32x4){0.f, 0.f, 0.f, 0.f};
            int kc0 = w * 25;
            int kcN = (w < 3) ? 25 : 23;
            for (int kc = 0; kc < kcN; ++kc) {
                int kg = kc0 + kc;
                int aB = (l15 == 0) ? (PL + (kg >> 1) * 264 + 128 + (kg & 1) * 64 + q16) : Z512;
                f16x8 B = *(const f16x8*)(SHC + aB);
                #pragma unroll
                for (int mi = 0; mi < 4; ++mi) {
                    int frag = ((kg * 4 + mi) << 9) + lane * 8;
                    f16x8 Ah = *(const f16x8*)(fchi + frag);
                    f16x8 Al = *(const f16x8*)(fclo + frag);
                    afc[mi] = __builtin_amdgcn_mfma_f32_16x16x32_f16(Al, B, afc[mi], 0, 0, 0);
                    afc[mi] = __builtin_amdgcn_mfma_f32_16x16x32_f16(Ah, B, afc[mi], 0, 0, 0);
                }
            }
            if (l15 == 0) {
                #pragma unroll
                for (int mi = 0; mi < 4; ++mi)
                    *(f32x4*)(SHC + FCP + w * 256 + mi * 64 + q16) = afc[mi];
            }
        }
        __syncthreads();                   // fc partials visible
        if (tid < 64) {
            int c = tid;
            const float* fp = (const float*)(SHC + FCP);
            float lg = fp[c] + fp[64 + c] + fp[128 + c] + fp[192 + c];
            float v = -3.4e38f;
            if (c < 50) { lg += fcb[c]; outS[t * 50 + c] = lg; v = lg; }
            int idx = c;
            #pragma unroll
            for (int off = 1; off < 64; off <<= 1) {
                float ov = __shfl_xor(v, off, 64);
                int   oi = __shfl_xor(idx, off, 64);
                if (ov > v || (ov == v && oi < idx)) { v = ov; idx = oi; }
            }
            if (c == 0) {
                int* pr = (int*)(SHC + PRD);
                pr[1] = pr[0];             // vp2 <- vp1
                pr[0] = idx;               // vp1 <- one-hot(pred)
            }
        }
        __syncthreads();                   // PRD visible; FCP reusable
    }
}

// ================= weight repack kernels =================
// OIHW conv weights -> A fragments [tap][kc][mi][lane][8], hi/lo f16 split
__global__ void repack_frags_k(const float* __restrict__ w, _Float16* __restrict__ ohi,
                               _Float16* __restrict__ olo, int ICS, int KMAX,
                               int NKC, int NMF, int total) {
    int i = blockIdx.x * 256 + threadIdx.x;
    if (i >= total) return;
    int j = i & 7, lane = (i >> 3) & 63;
    int rest = i >> 9;
    int mi = rest % NMF; rest /= NMF;
    int kc = rest % NKC; int tap = rest / NKC;
    int m = mi * 16 + (lane & 15);
    int k = kc * 32 + ((lane >> 4) & 3) * 8 + j;
    float v = (k < KMAX) ? w[((size_t)m * ICS + k) * 9 + tap] : 0.f;
    _Float16 hv = (_Float16)v;
    ohi[i] = hv; olo[i] = (_Float16)(v - (float)hv);
}

__global__ void repack_g1_k(const float* __restrict__ cx1w, const float* __restrict__ ch1w,
                            _Float16* __restrict__ ohi, _Float16* __restrict__ olo) {
    int i = blockIdx.x * 256 + threadIdx.x;
    if (i >= 294912) return;
    int j = i & 7; int lane = (i >> 3) & 63; int mt = (i >> 9) & 15;
    int rest = i >> 13; int kc = rest & 3; int tap = rest >> 2;
    int m = mt * 16 + (lane & 15);
    int kk = (lane >> 4) * 8 + j;
    float wv;
    if (kc < 2) wv = cx1w[((size_t)m * 64 + kc * 32 + kk) * 9 + tap];
    else        wv = ch1w[((size_t)m * 64 + (kc - 2) * 32 + kk) * 9 + tap];
    _Float16 hv = (_Float16)wv;
    ohi[i] = hv; olo[i] = (_Float16)(wv - (float)hv);
}

// fc weights [50][3136] -> frags [kc 98][mi 4][lane][8], k = p*64+ch
__global__ void repack_fc_k(const float* __restrict__ fcw, _Float16* __restrict__ ohi,
                            _Float16* __restrict__ olo) {
    int i = blockIdx.x * 256 + threadIdx.x;
    if (i >= 200704) return;
    int j = i & 7, lane = (i >> 3) & 63;
    int rest = i >> 9;
    int mi = rest & 3, kc = rest >> 2;
    int cls = mi * 16 + (lane & 15);
    int k = kc * 32 + ((lane >> 4) & 3) * 8 + j;
    int ch = k & 63, p = k >> 6;
    float v = (cls < 50) ? fcw[(size_t)cls * 3136 + ch * 49 + p] : 0.f;
    _Float16 hv = (_Float16)v;
    ohi[i] = hv; olo[i] = (_Float16)(v - (float)hv);
}

// one-hot conv tables: wv[tap][m] = cx0w[m, ic, tap]
__global__ void repack_wv_k(const float* __restrict__ cx0w, float* __restrict__ o, int ic) {
    int i = blockIdx.x * 256 + threadIdx.x;
    if (i >= 2304) return;
    int tap = i / 256, m = i % 256;
    o[i] = cx0w[((size_t)m * 131 + ic) * 9 + tap];
}

extern "C" void kernel_launch(void* const* d_in, const int* in_sizes, int n_in,
                              void* d_out, int out_size, void* d_ws, size_t ws_size,
                              hipStream_t stream)
{
    const float* x     = (const float*)d_in[0];
    const int*   fv    = (const int*)  d_in[1];
    const float* c0w   = (const float*)d_in[2];
    const float* c0b   = (const float*)d_in[3];
    const float* c1w   = (const float*)d_in[4];
    const float* c1b   = (const float*)d_in[5];
    const float* cx0w  = (const float*)d_in[6];
    const float* cx0b  = (const float*)d_in[7];
    const float* ch0w  = (const float*)d_in[8];
    const float* ch0b  = (const float*)d_in[9];
    const float* cx1w  = (const float*)d_in[10];
    const float* cx1b  = (const float*)d_in[11];
    const float* ch1w  = (const float*)d_in[12];
    const float* ch1b  = (const float*)d_in[13];
    const float* fcw   = (const float*)d_in[14];
    const float* fcb   = (const float*)d_in[15];
    float* out = (float*)d_out;
    const int n = in_sizes[0] / 12544;

    _Float16* h = (_Float16*)d_ws;
    _Float16* g0hi = h;                  // 147456 (NKC=2, NMF=16)
    _Float16* g0lo = g0hi + 147456;
    _Float16* g1hi = g0lo + 147456;      // 294912
    _Float16* g1lo = g1hi + 294912;
    _Float16* c0hi = g1lo + 294912;      // 294912
    _Float16* c0lo = c0hi + 294912;
    _Float16* c1hi = c0lo + 294912;      // 147456
    _Float16* c1lo = c1hi + 147456;
    _Float16* cshi = c1lo + 147456;      // 294912
    _Float16* cslo = cshi + 294912;
    _Float16* fchi = cslo + 294912;      // 200704
    _Float16* fclo = fchi + 200704;
    float*    wv1  = (float*)(fclo + 200704);   // 2304 f32 each
    float*    wvp1 = wv1 + 2304;
    float*    wvp2 = wvp1 + 2304;

    repack_frags_k<<<(147456 + 255) / 256, 256, 0, stream>>>(ch0w, g0hi, g0lo, 64, 64, 2, 16, 147456);
    repack_g1_k   <<<(294912 + 255) / 256, 256, 0, stream>>>(cx1w, ch1w, g1hi, g1lo);
    repack_frags_k<<<(294912 + 255) / 256, 256, 0, stream>>>(c0w, c0hi, c0lo, 256, 256, 8, 8, 294912);
    repack_frags_k<<<(147456 + 255) / 256, 256, 0, stream>>>(c1w, c1hi, c1lo, 128, 128, 4, 8, 147456);
    repack_frags_k<<<(294912 + 255) / 256, 256, 0, stream>>>(cx0w, cshi, cslo, 131, 128, 4, 16, 294912);
    repack_fc_k   <<<(200704 + 255) / 256, 256, 0, stream>>>(fcw, fchi, fclo);
    repack_wv_k   <<<(2304 + 255) / 256, 256, 0, stream>>>(cx0w, wv1, 130);
    repack_wv_k   <<<(2304 + 255) / 256, 256, 0, stream>>>(cx0w, wvp1, 129);
    repack_wv_k   <<<(2304 + 255) / 256, 256, 0, stream>>>(cx0w, wvp2, 128);

    (void)hipFuncSetAttribute((const void*)poly_fused,
                              hipFuncAttributeMaxDynamicSharedMemorySize, LDSB);
    poly_fused<<<n, 256, LDSB, stream>>>(x, fv, c0b, c1b, cx0b, ch0b, cx1b, ch1b, fcb,
                                         c0hi, c0lo, c1hi, c1lo, cshi, cslo,
                                         g0hi, g0lo, g1hi, g1lo, fchi, fclo,
                                         wv1, wvp1, wvp2, out);
}

// Round 6
// 13393.593 us; speedup vs baseline: 1.0105x; 1.0105x over previous
//
#include <hip/hip_runtime.h>
#include <hip/hip_fp16.h>

typedef float f32x4 __attribute__((ext_vector_type(4)));
typedef _Float16 f16x8 __attribute__((ext_vector_type(8)));
typedef _Float16 f16x4 __attribute__((ext_vector_type(4)));

// ---------------- LDS byte map (regions alias across phases) ----------------
// phase A: XP  @0..25872      x staged f16 [49][264ch] stride 528 (dies after conv0)
//          XF  @63936..76872  conv0 out [49][132] stride 264 (dies after conv1)
//          XF2 @0..12936      conv1 out (x_feat), aliases XP
//          ST  @12960..63920  static gates f32 [49 pix][stride 1040B] (written after cs conv)
// phase B: PL  @0..12936      planes [49][132]: h0 ch0..63 (byte 0..127), h1 (byte 128..255)
//          ST  persists; FCP fc partials @76896; PRD 2 ints @77920
// Z512 @77952: zeros, never written after init — OOW fallback for B loads
#define XP    0
#define XF    63936
#define XF2   0
#define PL    0
#define ST    12960
#define STSTR 1040
#define FCP   76896
#define PRD   77920
#define Z512  77952
#define LDSB  78464

__device__ __forceinline__ float sigmoidf_(float v) { return 1.0f / (1.0f + expf(-v)); }

// shifted-window conv GEMM, weights hi/lo f16 (A), acts single f16 (B):
// acc += Al*B + Ah*B  (weights exact via split; act error = f16 input quantization)
template <int NKC, int NMI>
__device__ __forceinline__ void conv_mfma_run(
    const char* __restrict__ SHb, int baseB, int pstr2,
    const int (&kofs)[NKC], int q16,
    const _Float16* __restrict__ ghi, const _Float16* __restrict__ glo,
    int NMF, int miBase, int miStep,
    const int (&okc)[4], const int (&py0)[4], const int (&px0)[4],
    f32x4 (&acc)[NMI][4], int lane)
{
    for (int dy = -1; dy <= 1; ++dy)
    for (int dx = -1; dx <= 1; ++dx) {
        const int tap = (dy + 1) * 3 + (dx + 1);
        int bb[4];
        #pragma unroll
        for (int n = 0; n < 4; ++n) {
            int py = py0[n] + dy, px = px0[n] + dx;
            bool ok = okc[n] && ((unsigned)py < 7u) && ((unsigned)px < 7u);
            bb[n] = ok ? baseB + (py * 7 + px) * pstr2 : Z512;  // Z512+kof<=Z512+496: zeros
        }
        #pragma unroll
        for (int kc = 0; kc < NKC; ++kc) {
            const int kof = kofs[kc] + q16;
            f16x8 B[4];
            #pragma unroll
            for (int n = 0; n < 4; ++n) B[n] = *(const f16x8*)(SHb + bb[n] + kof);
            #pragma unroll
            for (int ii = 0; ii < NMI; ++ii) {
                int frag = (((tap * NKC + kc) * NMF + (miBase + ii * miStep)) << 9) + lane * 8;
                f16x8 Ah = *(const f16x8*)(ghi + frag);
                f16x8 Al = *(const f16x8*)(glo + frag);
                #pragma unroll
                for (int n = 0; n < 4; ++n) {
                    acc[ii][n] = __builtin_amdgcn_mfma_f32_16x16x32_f16(Al, B[n], acc[ii][n], 0, 0, 0);
                    acc[ii][n] = __builtin_amdgcn_mfma_f32_16x16x32_f16(Ah, B[n], acc[ii][n], 0, 0, 0);
                }
            }
        }
    }
}

// one-hot map conv contribution injected at acc-init (map one-hot at pixel pv)
__device__ __forceinline__ void inject_onehot(
    f32x4 (&acc)[4][4], const float* __restrict__ wv, int pv,
    const int (&okc)[4], const int (&py0)[4], const int (&px0)[4], int w, int q)
{
    if (pv >= 49) return;                 // EOS / empty map
    int vy = pv / 7, vx = pv % 7;
    #pragma unroll
    for (int n = 0; n < 4; ++n) {
        int dy = vy - py0[n], dx = vx - px0[n];
        if (okc[n] && dy >= -1 && dy <= 1 && dx >= -1 && dx <= 1) {
            int tap = (dy + 1) * 3 + (dx + 1);
            const float* wp = wv + tap * 256 + w * 16 + q * 4;
            #pragma unroll
            for (int g = 0; g < 4; ++g)
                acc[g][n] += *(const f32x4*)(wp + g * 64);
        }
    }
}

extern "C" __global__ __launch_bounds__(256, 2)
void poly_fused(const float* __restrict__ x, const int* __restrict__ firstv,
                const float* __restrict__ b_c0, const float* __restrict__ b_c1,
                const float* __restrict__ cx0b, const float* __restrict__ ch0b,
                const float* __restrict__ cx1b, const float* __restrict__ ch1b,
                const float* __restrict__ fcb,
                const _Float16* __restrict__ c0hi, const _Float16* __restrict__ c0lo,
                const _Float16* __restrict__ c1hi, const _Float16* __restrict__ c1lo,
                const _Float16* __restrict__ cshi, const _Float16* __restrict__ cslo,
                const _Float16* __restrict__ g0hi, const _Float16* __restrict__ g0lo,
                const _Float16* __restrict__ g1hi, const _Float16* __restrict__ g1lo,
                const _Float16* __restrict__ fchi, const _Float16* __restrict__ fclo,
                const float* __restrict__ wv1,
                const float* __restrict__ wvp1, const float* __restrict__ wvp2,
                float* __restrict__ out)
{
    extern __shared__ char SHC[];
    float* SHf = (float*)SHC;
    const int tid = threadIdx.x, s = blockIdx.x;
    const int lane = tid & 63, w = tid >> 6;
    const int q = lane >> 4, l15 = lane & 15, q16 = q * 16;

    for (int i = tid; i < LDSB / 4; i += 256) SHf[i] = 0.f;
    __syncthreads();

    // per-lane column geometry (col = n*16 + l15; 49 live pixels)
    int okc[4], py0[4], px0[4];
    #pragma unroll
    for (int n = 0; n < 4; ++n) {
        int col = n * 16 + l15;
        okc[n] = col < 49;
        int p = okc[n] ? col : 0;
        py0[n] = p / 7; px0[n] = p % 7;
    }

    // ============ PHASE A ============
    const float* xs = x + (size_t)s * 12544;
    for (int e = tid; e < 12544; e += 256) {
        int ch = e / 49, p = e - ch * 49;
        *(_Float16*)(SHC + XP + p * 528 + ch * 2) = (_Float16)xs[e];
    }
    __syncthreads();                       // XP visible

    const int kofs8[8] = {0, 64, 128, 192, 256, 320, 384, 448};
    const int kofs4[4] = {0, 64, 128, 192};
    const int kofs2[2] = {0, 64};

    // conv0: M=128 (8 mfrags; wave owns w*2, w*2+1), K=256
    {
        f32x4 acc2[2][4];
        #pragma unroll
        for (int ii = 0; ii < 2; ++ii)
            #pragma unroll
            for (int n = 0; n < 4; ++n) acc2[ii][n] = (f32x4){0.f, 0.f, 0.f, 0.f};
        conv_mfma_run<8, 2>(SHC, XP, 528, kofs8, q16, c0hi, c0lo,
                            8, w * 2, 1, okc, py0, px0, acc2, lane);
        #pragma unroll
        for (int ii = 0; ii < 2; ++ii) {
            f32x4 bb = *(const f32x4*)(b_c0 + (w * 2 + ii) * 16 + q * 4);
            int chB = ((w * 2 + ii) * 16 + q * 4) * 2;
            #pragma unroll
            for (int n = 0; n < 4; ++n) if (okc[n]) {
                int p = n * 16 + l15;
                f16x4 h;
                #pragma unroll
                for (int r = 0; r < 4; ++r)
                    h[r] = (_Float16)fmaxf(acc2[ii][n][r] + bb[r], 0.f);
                *(f16x4*)(SHC + XF + p * 264 + chB) = h;
            }
        }
    }
    __syncthreads();                       // XF visible; XP dead

    // conv1: M=128, K=128, XF -> XF2 (aliases XP)
    {
        f32x4 acc2[2][4];
        #pragma unroll
        for (int ii = 0; ii < 2; ++ii)
            #pragma unroll
            for (int n = 0; n < 4; ++n) acc2[ii][n] = (f32x4){0.f, 0.f, 0.f, 0.f};
        conv_mfma_run<4, 2>(SHC, XF, 264, kofs4, q16, c1hi, c1lo,
                            8, w * 2, 1, okc, py0, px0, acc2, lane);
        #pragma unroll
        for (int ii = 0; ii < 2; ++ii) {
            f32x4 bb = *(const f32x4*)(b_c1 + (w * 2 + ii) * 16 + q * 4);
            int chB = ((w * 2 + ii) * 16 + q * 4) * 2;
            #pragma unroll
            for (int n = 0; n < 4; ++n) if (okc[n]) {
                int p = n * 16 + l15;
                f16x4 h;
                #pragma unroll
                for (int r = 0; r < 4; ++r)
                    h[r] = (_Float16)fmaxf(acc2[ii][n][r] + bb[r], 0.f);
                *(f16x4*)(SHC + XF2 + p * 264 + chB) = h;
            }
        }
    }
    __syncthreads();                       // XF2 visible; XF dead

    // static gates -> ST in LDS: st = conv_cs(x_feat) + (cx0b+ch0b) + v_first window
    const int fv = firstv[s];
    {
        f32x4 acc[4][4];
        #pragma unroll
        for (int g = 0; g < 4; ++g)
            #pragma unroll
            for (int n = 0; n < 4; ++n) acc[g][n] = (f32x4){0.f, 0.f, 0.f, 0.f};
        conv_mfma_run<4, 4>(SHC, XF2, 264, kofs4, q16, cshi, cslo,
                            16, w, 4, okc, py0, px0, acc, lane);
        const int fy = fv / 7, fx = fv % 7;
        #pragma unroll
        for (int g = 0; g < 4; ++g) {
            int m0 = g * 64 + w * 16 + q * 4;
            f32x4 b0 = *(const f32x4*)(cx0b + m0);
            f32x4 bh = *(const f32x4*)(ch0b + m0);
            #pragma unroll
            for (int n = 0; n < 4; ++n) {
                f32x4 v = acc[g][n] + b0 + bh;
                int dy = fy - py0[n], dx = fx - px0[n];
                if (okc[n] && dy >= -1 && dy <= 1 && dx >= -1 && dx <= 1) {
                    int tap = (dy + 1) * 3 + (dx + 1);
                    v += *(const f32x4*)(wv1 + tap * 256 + m0);
                }
                if (okc[n]) {
                    int p = n * 16 + l15;
                    *(f32x4*)(SHC + ST + p * STSTR + m0 * 4) = v;
                }
            }
        }
    }
    __syncthreads();                       // ST visible; XF2 dead

    // zero PL (aliases XF2) + init preds: vp1 = v_first, vp2 = empty(49)
    for (int i = tid; i < 12936 / 4; i += 256) SHf[i] = 0.f;
    if (tid == 0) { ((int*)(SHC + PRD))[0] = fv; ((int*)(SHC + PRD))[1] = 49; }
    __syncthreads();

    // layer-1 biases cached in registers
    f32x4 b1[4];
    #pragma unroll
    for (int g = 0; g < 4; ++g) {
        int m0 = g * 64 + w * 16 + q * 4;
        b1[g] = *(const f32x4*)(cx1b + m0) + *(const f32x4*)(ch1b + m0);
    }

    float c0s[4][4], c1s[4][4];
    #pragma unroll
    for (int n = 0; n < 4; ++n)
        #pragma unroll
        for (int r = 0; r < 4; ++r) { c0s[n][r] = 0.f; c1s[n][r] = 0.f; }

    float* outS = out + (size_t)s * 450;

    // ============ PHASE B: 9 recurrent steps ============
    for (int t = 0; t < 9; ++t) {
        f32x4 acc[4][4];
        // ---- L0 gates: acc = ST + vp1/vp2 injections; conv over h0 (K=64) ----
        #pragma unroll
        for (int g = 0; g < 4; ++g) {
            int m0 = g * 64 + w * 16 + q * 4;
            #pragma unroll
            for (int n = 0; n < 4; ++n) {
                int p = okc[n] ? (n * 16 + l15) : 0;
                acc[g][n] = *(const f32x4*)(SHC + ST + p * STSTR + m0 * 4);
            }
        }
        {
            int p1 = ((const int*)(SHC + PRD))[0];
            int p2 = ((const int*)(SHC + PRD))[1];
            inject_onehot(acc, wvp1, p1, okc, py0, px0, w, q);
            inject_onehot(acc, wvp2, p2, okc, py0, px0, w, q);
        }
        conv_mfma_run<2, 4>(SHC, PL, 264, kofs2, q16, g0hi, g0lo,
                            16, w, 4, okc, py0, px0, acc, lane);
        __syncthreads();                   // L0 reads of h0 done
        {   // L0 LSTM epilogue (in-lane), write h0 f16
            int chB = (w * 16 + q * 4) * 2;
            #pragma unroll
            for (int n = 0; n < 4; ++n) if (okc[n]) {
                int p = n * 16 + l15;
                f16x4 h;
                #pragma unroll
                for (int r = 0; r < 4; ++r) {
                    float ig = sigmoidf_(acc[0][n][r]);
                    float fg = sigmoidf_(acc[1][n][r]);
                    float gg = tanhf(acc[2][n][r]);
                    float og = sigmoidf_(acc[3][n][r]);
                    float cy = fg * c0s[n][r] + ig * gg;
                    c0s[n][r] = cy;
                    h[r] = (_Float16)(og * tanhf(cy));
                }
                *(f16x4*)(SHC + PL + p * 264 + chB) = h;
            }
        }
        __syncthreads();                   // h0 visible
        // ---- L1 gates: K = [h0 new | h1 old] = PL ch 0..127 ----
        #pragma unroll
        for (int g = 0; g < 4; ++g)
            #pragma unroll
            for (int n = 0; n < 4; ++n) acc[g][n] = b1[g];
        conv_mfma_run<4, 4>(SHC, PL, 264, kofs4, q16, g1hi, g1lo,
                            16, w, 4, okc, py0, px0, acc, lane);
        __syncthreads();                   // L1 reads of h1-old done
        {   // L1 LSTM epilogue, write h1 f16
            int chB = 128 + (w * 16 + q * 4) * 2;
            #pragma unroll
            for (int n = 0; n < 4; ++n) if (okc[n]) {
                int p = n * 16 + l15;
                f16x4 h;
                #pragma unroll
                for (int r = 0; r < 4; ++r) {
                    float ig = sigmoidf_(acc[0][n][r]);
                    float fg = sigmoidf_(acc[1][n][r]);
                    float gg = tanhf(acc[2][n][r]);
                    float og = sigmoidf_(acc[3][n][r]);
                    float cy = fg * c1s[n][r] + ig * gg;
                    c1s[n][r] = cy;
                    h[r] = (_Float16)(og * tanhf(cy));
                }
                *(f16x4*)(SHC + PL + p * 264 + chB) = h;
            }
        }
        __syncthreads();                   // h1 visible (fc input)
        {   // fc via MFMA: M=64 (50 live), K=3136 from PL h1; col 0 live
            f32x4 afc[4];
            #pragma unroll
            for (int mi = 0; mi < 4; ++mi) afc[mi] = (f32x4){0.f, 0.f, 0.f, 0.f};
            int kc0 = w * 25;
            int kcN = (w < 3) ? 25 : 23;
            for (int kc = 0; kc < kcN; ++kc) {
                int kg = kc0 + kc;
                int aB = (l15 == 0) ? (PL + (kg >> 1) * 264 + 128 + (kg & 1) * 64 + q16) : Z512;
                f16x8 B = *(const f16x8*)(SHC + aB);
                #pragma unroll
                for (int mi = 0; mi < 4; ++mi) {
                    int frag = ((kg * 4 + mi) << 9) + lane * 8;
                    f16x8 Ah = *(const f16x8*)(fchi + frag);
                    f16x8 Al = *(const f16x8*)(fclo + frag);
                    afc[mi] = __builtin_amdgcn_mfma_f32_16x16x32_f16(Al, B, afc[mi], 0, 0, 0);
                    afc[mi] = __builtin_amdgcn_mfma_f32_16x16x32_f16(Ah, B, afc[mi], 0, 0, 0);
                }
            }
            if (l15 == 0) {
                #pragma unroll
                for (int mi = 0; mi < 4; ++mi)
                    *(f32x4*)(SHC + FCP + w * 256 + mi * 64 + q16) = afc[mi];
            }
        }
        __syncthreads();                   // fc partials visible
        if (tid < 64) {
            int c = tid;
            const float* fp = (const float*)(SHC + FCP);
            float lg = fp[c] + fp[64 + c] + fp[128 + c] + fp[192 + c];
            float v = -3.4e38f;
            if (c < 50) { lg += fcb[c]; outS[t * 50 + c] = lg; v = lg; }
            int idx = c;
            #pragma unroll
            for (int off = 1; off < 64; off <<= 1) {
                float ov = __shfl_xor(v, off, 64);
                int   oi = __shfl_xor(idx, off, 64);
                if (ov > v || (ov == v && oi < idx)) { v = ov; idx = oi; }
            }
            if (c == 0) {
                int* pr = (int*)(SHC + PRD);
                pr[1] = pr[0];             // vp2 <- vp1
                pr[0] = idx;               // vp1 <- one-hot(pred)
            }
        }
        __syncthreads();                   // PRD visible; FCP reusable
    }
}

// ================= weight repack kernels =================
// OIHW conv weights -> A fragments [tap][kc][mi][lane][8], hi/lo f16 split
__global__ void repack_frags_k(const float* __restrict__ w, _Float16* __restrict__ ohi,
                               _Float16* __restrict__ olo, int ICS, int KMAX,
                               int NKC, int NMF, int total) {
    int i = blockIdx.x * 256 + threadIdx.x;
    if (i >= total) return;
    int j = i & 7, lane = (i >> 3) & 63;
    int rest = i >> 9;
    int mi = rest % NMF; rest /= NMF;
    int kc = rest % NKC; int tap = rest / NKC;
    int m = mi * 16 + (lane & 15);
    int k = kc * 32 + ((lane >> 4) & 3) * 8 + j;
    float v = (k < KMAX) ? w[((size_t)m * ICS + k) * 9 + tap] : 0.f;
    _Float16 hv = (_Float16)v;
    ohi[i] = hv; olo[i] = (_Float16)(v - (float)hv);
}

__global__ void repack_g1_k(const float* __restrict__ cx1w, const float* __restrict__ ch1w,
                            _Float16* __restrict__ ohi, _Float16* __restrict__ olo) {
    int i = blockIdx.x * 256 + threadIdx.x;
    if (i >= 294912) return;
    int j = i & 7; int lane = (i >> 3) & 63; int mt = (i >> 9) & 15;
    int rest = i >> 13; int kc = rest & 3; int tap = rest >> 2;
    int m = mt * 16 + (lane & 15);
    int kk = (lane >> 4) * 8 + j;
    float wv;
    if (kc < 2) wv = cx1w[((size_t)m * 64 + kc * 32 + kk) * 9 + tap];
    else        wv = ch1w[((size_t)m * 64 + (kc - 2) * 32 + kk) * 9 + tap];
    _Float16 hv = (_Float16)wv;
    ohi[i] = hv; olo[i] = (_Float16)(wv - (float)hv);
}

// fc weights [50][3136] -> frags [kc 98][mi 4][lane][8], k = p*64+ch
__global__ void repack_fc_k(const float* __restrict__ fcw, _Float16* __restrict__ ohi,
                            _Float16* __restrict__ olo) {
    int i = blockIdx.x * 256 + threadIdx.x;
    if (i >= 200704) return;
    int j = i & 7, lane = (i >> 3) & 63;
    int rest = i >> 9;
    int mi = rest & 3, kc = rest >> 2;
    int cls = mi * 16 + (lane & 15);
    int k = kc * 32 + ((lane >> 4) & 3) * 8 + j;
    int ch = k & 63, p = k >> 6;
    float v = (cls < 50) ? fcw[(size_t)cls * 3136 + ch * 49 + p] : 0.f;
    _Float16 hv = (_Float16)v;
    ohi[i] = hv; olo[i] = (_Float16)(v - (float)hv);
}

// one-hot conv tables: wv[tap][m] = cx0w[m, ic, tap]
__global__ void repack_wv_k(const float* __restrict__ cx0w, float* __restrict__ o, int ic) {
    int i = blockIdx.x * 256 + threadIdx.x;
    if (i >= 2304) return;
    int tap = i / 256, m = i % 256;
    o[i] = cx0w[((size_t)m * 131 + ic) * 9 + tap];
}

extern "C" void kernel_launch(void* const* d_in, const int* in_sizes, int n_in,
                              void* d_out, int out_size, void* d_ws, size_t ws_size,
                              hipStream_t stream)
{
    const float* x     = (const float*)d_in[0];
    const int*   fv    = (const int*)  d_in[1];
    const float* c0w   = (const float*)d_in[2];
    const float* c0b   = (const float*)d_in[3];
    const float* c1w   = (const float*)d_in[4];
    const float* c1b   = (const float*)d_in[5];
    const float* cx0w  = (const float*)d_in[6];
    const float* cx0b  = (const float*)d_in[7];
    const float* ch0w  = (const float*)d_in[8];
    const float* ch0b  = (const float*)d_in[9];
    const float* cx1w  = (const float*)d_in[10];
    const float* cx1b  = (const float*)d_in[11];
    const float* ch1w  = (const float*)d_in[12];
    const float* ch1b  = (const float*)d_in[13];
    const float* fcw   = (const float*)d_in[14];
    const float* fcb   = (const float*)d_in[15];
    float* out = (float*)d_out;
    const int n = in_sizes[0] / 12544;

    _Float16* h = (_Float16*)d_ws;
    _Float16* g0hi = h;                  // 147456 (NKC=2, NMF=16)
    _Float16* g0lo = g0hi + 147456;
    _Float16* g1hi = g0lo + 147456;      // 294912
    _Float16* g1lo = g1hi + 294912;
    _Float16* c0hi = g1lo + 294912;      // 294912
    _Float16* c0lo = c0hi + 294912;
    _Float16* c1hi = c0lo + 294912;      // 147456
    _Float16* c1lo = c1hi + 147456;
    _Float16* cshi = c1lo + 147456;      // 294912
    _Float16* cslo = cshi + 294912;
    _Float16* fchi = cslo + 294912;      // 200704
    _Float16* fclo = fchi + 200704;
    float*    wv1  = (float*)(fclo + 200704);   // 2304 f32 each
    float*    wvp1 = wv1 + 2304;
    float*    wvp2 = wvp1 + 2304;

    repack_frags_k<<<(147456 + 255) / 256, 256, 0, stream>>>(ch0w, g0hi, g0lo, 64, 64, 2, 16, 147456);
    repack_g1_k   <<<(294912 + 255) / 256, 256, 0, stream>>>(cx1w, ch1w, g1hi, g1lo);
    repack_frags_k<<<(294912 + 255) / 256, 256, 0, stream>>>(c0w, c0hi, c0lo, 256, 256, 8, 8, 294912);
    repack_frags_k<<<(147456 + 255) / 256, 256, 0, stream>>>(c1w, c1hi, c1lo, 128, 128, 4, 8, 147456);
    repack_frags_k<<<(294912 + 255) / 256, 256, 0, stream>>>(cx0w, cshi, cslo, 131, 128, 4, 16, 294912);
    repack_fc_k   <<<(200704 + 255) / 256, 256, 0, stream>>>(fcw, fchi, fclo);
    repack_wv_k   <<<(2304 + 255) / 256, 256, 0, stream>>>(cx0w, wv1, 130);
    repack_wv_k   <<<(2304 + 255) / 256, 256, 0, stream>>>(cx0w, wvp1, 129);
    repack_wv_k   <<<(2304 + 255) / 256, 256, 0, stream>>>(cx0w, wvp2, 128);

    (void)hipFuncSetAttribute((const void*)poly_fused,
                              hipFuncAttributeMaxDynamicSharedMemorySize, LDSB);
    poly_fused<<<n, 256, LDSB, stream>>>(x, fv, c0b, c1b, cx0b, ch0b, cx1b, ch1b, fcb,
                                         c0hi, c0lo, c1hi, c1lo, cshi, cslo,
                                         g0hi, g0lo, g1hi, g1lo, fchi, fclo,
                                         wv1, wvp1, wvp2, out);
}

// Round 7
// 5760.767 us; speedup vs baseline: 2.3493x; 2.3250x over previous
//
#include <hip/hip_runtime.h>
#include <hip/hip_fp16.h>

typedef float f32x4 __attribute__((ext_vector_type(4)));
typedef _Float16 f16x8 __attribute__((ext_vector_type(8)));
typedef _Float16 f16x4 __attribute__((ext_vector_type(4)));

// ---------------- LDS byte map (regions alias across phases) ----------------
// phase A: XP  @0..25872      x staged f16 [49][264ch] stride 528 (dies after conv0)
//          XF  @63936..76872  conv0 out [49][132] stride 264 (dies after conv1)
//          XF2 @0..12936      conv1 out (x_feat), aliases XP
//          ST  @12960..63920  static gates f32 [49 pix][stride 1040B]
// phase B: PL  @0..12936      planes [49][132]: h0 ch0..63 (byte 0..127), h1 (128..255)
//          ST persists; FCP fc partials @76896; PRD 2 ints @77920
// Z512 @77952: zeros, never written after init — OOW fallback for B loads
#define XP    0
#define XF    63936
#define XF2   0
#define PL    0
#define ST    12960
#define STSTR 1040
#define FCP   76896
#define PRD   77920
#define Z512  77952
#define LDSB  78464

__device__ __forceinline__ float sigmoidf_(float v) { return 1.0f / (1.0f + expf(-v)); }

// shifted-window conv GEMM, weights hi/lo f16 (A), acts single f16 (B):
// acc += Al*B + Ah*B. Tap loop deliberately NOT unrolled: keeps the
// scheduling window small so the allocator doesn't hoist 9 taps' worth of
// loads and spill acc to scratch (round-5/6 failure mode: 6.5 GB scratch).
template <int NKC, int NMI>
__device__ __forceinline__ void conv_mfma_run(
    const char* __restrict__ SHb, int baseB, int pstr2,
    const int (&kofs)[NKC], int q16,
    const _Float16* __restrict__ ghi, const _Float16* __restrict__ glo,
    int NMF, int miBase, int miStep,
    const int (&okc)[4], const int (&py0)[4], const int (&px0)[4],
    f32x4 (&acc)[NMI][4], int lane)
{
    #pragma unroll 1
    for (int tap = 0; tap < 9; ++tap) {
        const int dy = tap / 3 - 1, dx = tap % 3 - 1;
        int bb[4];
        #pragma unroll
        for (int n = 0; n < 4; ++n) {
            int py = py0[n] + dy, px = px0[n] + dx;
            bool ok = okc[n] && ((unsigned)py < 7u) && ((unsigned)px < 7u);
            bb[n] = ok ? baseB + (py * 7 + px) * pstr2 : Z512;  // Z512+kof<=Z512+496: zeros
        }
        #pragma unroll
        for (int kc = 0; kc < NKC; ++kc) {
            const int kof = kofs[kc] + q16;
            f16x8 B[4];
            #pragma unroll
            for (int n = 0; n < 4; ++n) B[n] = *(const f16x8*)(SHb + bb[n] + kof);
            #pragma unroll
            for (int ii = 0; ii < NMI; ++ii) {
                int frag = (((tap * NKC + kc) * NMF + (miBase + ii * miStep)) << 9) + lane * 8;
                f16x8 Ah = *(const f16x8*)(ghi + frag);
                f16x8 Al = *(const f16x8*)(glo + frag);
                #pragma unroll
                for (int n = 0; n < 4; ++n) {
                    acc[ii][n] = __builtin_amdgcn_mfma_f32_16x16x32_f16(Al, B[n], acc[ii][n], 0, 0, 0);
                    acc[ii][n] = __builtin_amdgcn_mfma_f32_16x16x32_f16(Ah, B[n], acc[ii][n], 0, 0, 0);
                }
            }
        }
    }
}

// one-hot map conv contribution injected at acc-init (map one-hot at pixel pv)
__device__ __forceinline__ void inject_onehot(
    f32x4 (&acc)[4][4], const float* __restrict__ wv, int pv,
    const int (&okc)[4], const int (&py0)[4], const int (&px0)[4], int w, int q)
{
    if (pv >= 49) return;                 // EOS / empty map
    int vy = pv / 7, vx = pv % 7;
    #pragma unroll
    for (int n = 0; n < 4; ++n) {
        int dy = vy - py0[n], dx = vx - px0[n];
        if (okc[n] && dy >= -1 && dy <= 1 && dx >= -1 && dx <= 1) {
            int tap = (dy + 1) * 3 + (dx + 1);
            const float* wp = wv + tap * 256 + w * 16 + q * 4;
            #pragma unroll
            for (int g = 0; g < 4; ++g)
                acc[g][n] += *(const f32x4*)(wp + g * 64);
        }
    }
}

extern "C" __global__ __launch_bounds__(256, 1)
void poly_fused(const float* __restrict__ x, const int* __restrict__ firstv,
                const float* __restrict__ b_c0, const float* __restrict__ b_c1,
                const float* __restrict__ cx0b, const float* __restrict__ ch0b,
                const float* __restrict__ cx1b, const float* __restrict__ ch1b,
                const float* __restrict__ fcb,
                const _Float16* __restrict__ c0hi, const _Float16* __restrict__ c0lo,
                const _Float16* __restrict__ c1hi, const _Float16* __restrict__ c1lo,
                const _Float16* __restrict__ cshi, const _Float16* __restrict__ cslo,
                const _Float16* __restrict__ g0hi, const _Float16* __restrict__ g0lo,
                const _Float16* __restrict__ g1hi, const _Float16* __restrict__ g1lo,
                const _Float16* __restrict__ fchi, const _Float16* __restrict__ fclo,
                const float* __restrict__ wv1,
                const float* __restrict__ wvp1, const float* __restrict__ wvp2,
                float* __restrict__ out)
{
    extern __shared__ char SHC[];
    float* SHf = (float*)SHC;
    const int tid = threadIdx.x, s = blockIdx.x;
    const int lane = tid & 63, w = tid >> 6;
    const int q = lane >> 4, l15 = lane & 15, q16 = q * 16;

    for (int i = tid; i < LDSB / 4; i += 256) SHf[i] = 0.f;
    __syncthreads();

    // per-lane column geometry (col = n*16 + l15; 49 live pixels)
    int okc[4], py0[4], px0[4];
    #pragma unroll
    for (int n = 0; n < 4; ++n) {
        int col = n * 16 + l15;
        okc[n] = col < 49;
        int p = okc[n] ? col : 0;
        py0[n] = p / 7; px0[n] = p % 7;
    }

    // ============ PHASE A ============
    const float* xs = x + (size_t)s * 12544;
    for (int e = tid; e < 12544; e += 256) {
        int ch = e / 49, p = e - ch * 49;
        *(_Float16*)(SHC + XP + p * 528 + ch * 2) = (_Float16)xs[e];
    }
    __syncthreads();                       // XP visible

    const int kofs8[8] = {0, 64, 128, 192, 256, 320, 384, 448};
    const int kofs4[4] = {0, 64, 128, 192};
    const int kofs2[2] = {0, 64};

    // conv0: M=128 (8 mfrags; wave owns w*2, w*2+1), K=256
    {
        f32x4 acc2[2][4];
        #pragma unroll
        for (int ii = 0; ii < 2; ++ii)
            #pragma unroll
            for (int n = 0; n < 4; ++n) acc2[ii][n] = (f32x4){0.f, 0.f, 0.f, 0.f};
        conv_mfma_run<8, 2>(SHC, XP, 528, kofs8, q16, c0hi, c0lo,
                            8, w * 2, 1, okc, py0, px0, acc2, lane);
        #pragma unroll
        for (int ii = 0; ii < 2; ++ii) {
            f32x4 bb = *(const f32x4*)(b_c0 + (w * 2 + ii) * 16 + q * 4);
            int chB = ((w * 2 + ii) * 16 + q * 4) * 2;
            #pragma unroll
            for (int n = 0; n < 4; ++n) if (okc[n]) {
                int p = n * 16 + l15;
                f16x4 h;
                #pragma unroll
                for (int r = 0; r < 4; ++r)
                    h[r] = (_Float16)fmaxf(acc2[ii][n][r] + bb[r], 0.f);
                *(f16x4*)(SHC + XF + p * 264 + chB) = h;
            }
        }
    }
    __syncthreads();                       // XF visible; XP dead

    // conv1: M=128, K=128, XF -> XF2 (aliases XP)
    {
        f32x4 acc2[2][4];
        #pragma unroll
        for (int ii = 0; ii < 2; ++ii)
            #pragma unroll
            for (int n = 0; n < 4; ++n) acc2[ii][n] = (f32x4){0.f, 0.f, 0.f, 0.f};
        conv_mfma_run<4, 2>(SHC, XF, 264, kofs4, q16, c1hi, c1lo,
                            8, w * 2, 1, okc, py0, px0, acc2, lane);
        #pragma unroll
        for (int ii = 0; ii < 2; ++ii) {
            f32x4 bb = *(const f32x4*)(b_c1 + (w * 2 + ii) * 16 + q * 4);
            int chB = ((w * 2 + ii) * 16 + q * 4) * 2;
            #pragma unroll
            for (int n = 0; n < 4; ++n) if (okc[n]) {
                int p = n * 16 + l15;
                f16x4 h;
                #pragma unroll
                for (int r = 0; r < 4; ++r)
                    h[r] = (_Float16)fmaxf(acc2[ii][n][r] + bb[r], 0.f);
                *(f16x4*)(SHC + XF2 + p * 264 + chB) = h;
            }
        }
    }
    __syncthreads();                       // XF2 visible; XF dead

    // static gates -> ST in LDS: st = conv_cs(x_feat) + (cx0b+ch0b) + v_first window
    const int fv = firstv[s];
    {
        f32x4 acc[4][4];
        #pragma unroll
        for (int g = 0; g < 4; ++g)
            #pragma unroll
            for (int n = 0; n < 4; ++n) acc[g][n] = (f32x4){0.f, 0.f, 0.f, 0.f};
        conv_mfma_run<4, 4>(SHC, XF2, 264, kofs4, q16, cshi, cslo,
                            16, w, 4, okc, py0, px0, acc, lane);
        const int fy = fv / 7, fx = fv % 7;
        #pragma unroll
        for (int g = 0; g < 4; ++g) {
            int m0 = g * 64 + w * 16 + q * 4;
            f32x4 b0 = *(const f32x4*)(cx0b + m0);
            f32x4 bh = *(const f32x4*)(ch0b + m0);
            #pragma unroll
            for (int n = 0; n < 4; ++n) {
                f32x4 v = acc[g][n] + b0 + bh;
                int dy = fy - py0[n], dx = fx - px0[n];
                if (okc[n] && dy >= -1 && dy <= 1 && dx >= -1 && dx <= 1) {
                    int tap = (dy + 1) * 3 + (dx + 1);
                    v += *(const f32x4*)(wv1 + tap * 256 + m0);
                }
                if (okc[n]) {
                    int p = n * 16 + l15;
                    *(f32x4*)(SHC + ST + p * STSTR + m0 * 4) = v;
                }
            }
        }
    }
    __syncthreads();                       // ST visible; XF2 dead

    // zero PL (aliases XF2) + init preds: vp1 = v_first, vp2 = empty(49)
    for (int i = tid; i < 12936 / 4; i += 256) SHf[i] = 0.f;
    if (tid == 0) { ((int*)(SHC + PRD))[0] = fv; ((int*)(SHC + PRD))[1] = 49; }
    __syncthreads();

    // layer-1 biases cached in registers
    f32x4 b1[4];
    #pragma unroll
    for (int g = 0; g < 4; ++g) {
        int m0 = g * 64 + w * 16 + q * 4;
        b1[g] = *(const f32x4*)(cx1b + m0) + *(const f32x4*)(ch1b + m0);
    }

    float c0s[4][4], c1s[4][4];
    #pragma unroll
    for (int n = 0; n < 4; ++n)
        #pragma unroll
        for (int r = 0; r < 4; ++r) { c0s[n][r] = 0.f; c1s[n][r] = 0.f; }

    float* outS = out + (size_t)s * 450;

    // ============ PHASE B: 9 recurrent steps ============
    for (int t = 0; t < 9; ++t) {
        f32x4 acc[4][4];
        // ---- L0 gates: acc = ST + vp1/vp2 injections; conv over h0 (K=64) ----
        #pragma unroll
        for (int g = 0; g < 4; ++g) {
            int m0 = g * 64 + w * 16 + q * 4;
            #pragma unroll
            for (int n = 0; n < 4; ++n) {
                int p = okc[n] ? (n * 16 + l15) : 0;
                acc[g][n] = *(const f32x4*)(SHC + ST + p * STSTR + m0 * 4);
            }
        }
        {
            int p1 = ((const int*)(SHC + PRD))[0];
            int p2 = ((const int*)(SHC + PRD))[1];
            inject_onehot(acc, wvp1, p1, okc, py0, px0, w, q);
            inject_onehot(acc, wvp2, p2, okc, py0, px0, w, q);
        }
        conv_mfma_run<2, 4>(SHC, PL, 264, kofs2, q16, g0hi, g0lo,
                            16, w, 4, okc, py0, px0, acc, lane);
        __syncthreads();                   // L0 reads of h0 done
        {   // L0 LSTM epilogue (in-lane), write h0 f16
            int chB = (w * 16 + q * 4) * 2;
            #pragma unroll
            for (int n = 0; n < 4; ++n) if (okc[n]) {
                int p = n * 16 + l15;
                f16x4 h;
                #pragma unroll
                for (int r = 0; r < 4; ++r) {
                    float ig = sigmoidf_(acc[0][n][r]);
                    float fg = sigmoidf_(acc[1][n][r]);
                    float gg = tanhf(acc[2][n][r]);
                    float og = sigmoidf_(acc[3][n][r]);
                    float cy = fg * c0s[n][r] + ig * gg;
                    c0s[n][r] = cy;
                    h[r] = (_Float16)(og * tanhf(cy));
                }
                *(f16x4*)(SHC + PL + p * 264 + chB) = h;
            }
        }
        __syncthreads();                   // h0 visible
        // ---- L1 gates: K = [h0 new | h1 old] = PL ch 0..127 ----
        #pragma unroll
        for (int g = 0; g < 4; ++g)
            #pragma unroll
            for (int n = 0; n < 4; ++n) acc[g][n] = b1[g];
        conv_mfma_run<4, 4>(SHC, PL, 264, kofs4, q16, g1hi, g1lo,
                            16, w, 4, okc, py0, px0, acc, lane);
        __syncthreads();                   // L1 reads of h1-old done
        {   // L1 LSTM epilogue, write h1 f16
            int chB = 128 + (w * 16 + q * 4) * 2;
            #pragma unroll
            for (int n = 0; n < 4; ++n) if (okc[n]) {
                int p = n * 16 + l15;
                f16x4 h;
                #pragma unroll
                for (int r = 0; r < 4; ++r) {
                    float ig = sigmoidf_(acc[0][n][r]);
                    float fg = sigmoidf_(acc[1][n][r]);
                    float gg = tanhf(acc[2][n][r]);
                    float og = sigmoidf_(acc[3][n][r]);
                    float cy = fg * c1s[n][r] + ig * gg;
                    c1s[n][r] = cy;
                    h[r] = (_Float16)(og * tanhf(cy));
                }
                *(f16x4*)(SHC + PL + p * 264 + chB) = h;
            }
        }
        __syncthreads();                   // h1 visible (fc input)
        {   // fc via MFMA: M=64 (50 live), K=3136 from PL h1; col 0 live
            f32x4 afc[4];
            #pragma unroll
            for (int mi = 0; mi < 4; ++mi) afc[mi] = (f32x4){0.f, 0.f, 0.f, 0.f};
            int kc0 = w * 25;
            int kcN = (w < 3) ? 25 : 23;
            #pragma unroll 1
            for (int kc = 0; kc < kcN; ++kc) {
                int kg = kc0 + kc;
                int aB = (l15 == 0) ? (PL + (kg >> 1) * 264 + 128 + (kg & 1) * 64 + q16) : Z512;
                f16x8 B = *(const f16x8*)(SHC + aB);
                #pragma unroll
                for (int mi = 0; mi < 4; ++mi) {
                    int frag = ((kg * 4 + mi) << 9) + lane * 8;
                    f16x8 Ah = *(const f16x8*)(fchi + frag);
                    f16x8 Al = *(const f16x8*)(fclo + frag);
                    afc[mi] = __builtin_amdgcn_mfma_f32_16x16x32_f16(Al, B, afc[mi], 0, 0, 0);
                    afc[mi] = __builtin_amdgcn_mfma_f32_16x16x32_f16(Ah, B, afc[mi], 0, 0, 0);
                }
            }
            if (l15 == 0) {
                #pragma unroll
                for (int mi = 0; mi < 4; ++mi)
                    *(f32x4*)(SHC + FCP + w * 256 + mi * 64 + q16) = afc[mi];
            }
        }
        __syncthreads();                   // fc partials visible
        if (tid < 64) {
            int c = tid;
            const float* fp = (const float*)(SHC + FCP);
            float lg = fp[c] + fp[64 + c] + fp[128 + c] + fp[192 + c];
            float v = -3.4e38f;
            if (c < 50) { lg += fcb[c]; outS[t * 50 + c] = lg; v = lg; }
            int idx = c;
            #pragma unroll
            for (int off = 1; off < 64; off <<= 1) {
                float ov = __shfl_xor(v, off, 64);
                int   oi = __shfl_xor(idx, off, 64);
                if (ov > v || (ov == v && oi < idx)) { v = ov; idx = oi; }
            }
            if (c == 0) {
                int* pr = (int*)(SHC + PRD);
                pr[1] = pr[0];             // vp2 <- vp1
                pr[0] = idx;               // vp1 <- one-hot(pred)
            }
        }
        __syncthreads();                   // PRD visible; FCP reusable
    }
}

// ================= weight repack kernels =================
// OIHW conv weights -> A fragments [tap][kc][mi][lane][8], hi/lo f16 split
__global__ void repack_frags_k(const float* __restrict__ w, _Float16* __restrict__ ohi,
                               _Float16* __restrict__ olo, int ICS, int KMAX,
                               int NKC, int NMF, int total) {
    int i = blockIdx.x * 256 + threadIdx.x;
    if (i >= total) return;
    int j = i & 7, lane = (i >> 3) & 63;
    int rest = i >> 9;
    int mi = rest % NMF; rest /= NMF;
    int kc = rest % NKC; int tap = rest / NKC;
    int m = mi * 16 + (lane & 15);
    int k = kc * 32 + ((lane >> 4) & 3) * 8 + j;
    float v = (k < KMAX) ? w[((size_t)m * ICS + k) * 9 + tap] : 0.f;
    _Float16 hv = (_Float16)v;
    ohi[i] = hv; olo[i] = (_Float16)(v - (float)hv);
}

__global__ void repack_g1_k(const float* __restrict__ cx1w, const float* __restrict__ ch1w,
                            _Float16* __restrict__ ohi, _Float16* __restrict__ olo) {
    int i = blockIdx.x * 256 + threadIdx.x;
    if (i >= 294912) return;
    int j = i & 7; int lane = (i >> 3) & 63; int mt = (i >> 9) & 15;
    int rest = i >> 13; int kc = rest & 3; int tap = rest >> 2;
    int m = mt * 16 + (lane & 15);
    int kk = (lane >> 4) * 8 + j;
    float wv;
    if (kc < 2) wv = cx1w[((size_t)m * 64 + kc * 32 + kk) * 9 + tap];
    else        wv = ch1w[((size_t)m * 64 + (kc - 2) * 32 + kk) * 9 + tap];
    _Float16 hv = (_Float16)wv;
    ohi[i] = hv; olo[i] = (_Float16)(wv - (float)hv);
}

// fc weights [50][3136] -> frags [kc 98][mi 4][lane][8], k = p*64+ch
__global__ void repack_fc_k(const float* __restrict__ fcw, _Float16* __restrict__ ohi,
                            _Float16* __restrict__ olo) {
    int i = blockIdx.x * 256 + threadIdx.x;
    if (i >= 200704) return;
    int j = i & 7, lane = (i >> 3) & 63;
    int rest = i >> 9;
    int mi = rest & 3, kc = rest >> 2;
    int cls = mi * 16 + (lane & 15);
    int k = kc * 32 + ((lane >> 4) & 3) * 8 + j;
    int ch = k & 63, p = k >> 6;
    float v = (cls < 50) ? fcw[(size_t)cls * 3136 + ch * 49 + p] : 0.f;
    _Float16 hv = (_Float16)v;
    ohi[i] = hv; olo[i] = (_Float16)(v - (float)hv);
}

// one-hot conv tables: wv[tap][m] = cx0w[m, ic, tap]
__global__ void repack_wv_k(const float* __restrict__ cx0w, float* __restrict__ o, int ic) {
    int i = blockIdx.x * 256 + threadIdx.x;
    if (i >= 2304) return;
    int tap = i / 256, m = i % 256;
    o[i] = cx0w[((size_t)m * 131 + ic) * 9 + tap];
}

extern "C" void kernel_launch(void* const* d_in, const int* in_sizes, int n_in,
                              void* d_out, int out_size, void* d_ws, size_t ws_size,
                              hipStream_t stream)
{
    const float* x     = (const float*)d_in[0];
    const int*   fv    = (const int*)  d_in[1];
    const float* c0w   = (const float*)d_in[2];
    const float* c0b   = (const float*)d_in[3];
    const float* c1w   = (const float*)d_in[4];
    const float* c1b   = (const float*)d_in[5];
    const float* cx0w  = (const float*)d_in[6];
    const float* cx0b  = (const float*)d_in[7];
    const float* ch0w  = (const float*)d_in[8];
    const float* ch0b  = (const float*)d_in[9];
    const float* cx1w  = (const float*)d_in[10];
    const float* cx1b  = (const float*)d_in[11];
    const float* ch1w  = (const float*)d_in[12];
    const float* ch1b  = (const float*)d_in[13];
    const float* fcw   = (const float*)d_in[14];
    const float* fcb   = (const float*)d_in[15];
    float* out = (float*)d_out;
    const int n = in_sizes[0] / 12544;

    _Float16* h = (_Float16*)d_ws;
    _Float16* g0hi = h;                  // 147456 (NKC=2, NMF=16)
    _Float16* g0lo = g0hi + 147456;
    _Float16* g1hi = g0lo + 147456;      // 294912
    _Float16* g1lo = g1hi + 294912;
    _Float16* c0hi = g1lo + 294912;      // 294912
    _Float16* c0lo = c0hi + 294912;
    _Float16* c1hi = c0lo + 294912;      // 147456
    _Float16* c1lo = c1hi + 147456;
    _Float16* cshi = c1lo + 147456;      // 294912
    _Float16* cslo = cshi + 294912;
    _Float16* fchi = cslo + 294912;      // 200704
    _Float16* fclo = fchi + 200704;
    float*    wv1  = (float*)(fclo + 200704);   // 2304 f32 each
    float*    wvp1 = wv1 + 2304;
    float*    wvp2 = wvp1 + 2304;

    repack_frags_k<<<(147456 + 255) / 256, 256, 0, stream>>>(ch0w, g0hi, g0lo, 64, 64, 2, 16, 147456);
    repack_g1_k   <<<(294912 + 255) / 256, 256, 0, stream>>>(cx1w, ch1w, g1hi, g1lo);
    repack_frags_k<<<(294912 + 255) / 256, 256, 0, stream>>>(c0w, c0hi, c0lo, 256, 256, 8, 8, 294912);
    repack_frags_k<<<(147456 + 255) / 256, 256, 0, stream>>>(c1w, c1hi, c1lo, 128, 128, 4, 8, 147456);
    repack_frags_k<<<(294912 + 255) / 256, 256, 0, stream>>>(cx0w, cshi, cslo, 131, 128, 4, 16, 294912);
    repack_fc_k   <<<(200704 + 255) / 256, 256, 0, stream>>>(fcw, fchi, fclo);
    repack_wv_k   <<<(2304 + 255) / 256, 256, 0, stream>>>(cx0w, wv1, 130);
    repack_wv_k   <<<(2304 + 255) / 256, 256, 0, stream>>>(cx0w, wvp1, 129);
    repack_wv_k   <<<(2304 + 255) / 256, 256, 0, stream>>>(cx0w, wvp2, 128);

    (void)hipFuncSetAttribute((const void*)poly_fused,
                              hipFuncAttributeMaxDynamicSharedMemorySize, LDSB);
    poly_fused<<<n, 256, LDSB, stream>>>(x, fv, c0b, c1b, cx0b, ch0b, cx1b, ch1b, fcb,
                                         c0hi, c0lo, c1hi, c1lo, cshi, cslo,
                                         g0hi, g0lo, g1hi, g1lo, fchi, fclo,
                                         wv1, wvp1, wvp2, out);
}

// Round 8
// 4986.926 us; speedup vs baseline: 2.7139x; 1.1552x over previous
//
#include <hip/hip_runtime.h>
#include <hip/hip_fp16.h>

typedef float f32x4 __attribute__((ext_vector_type(4)));
typedef _Float16 f16x8 __attribute__((ext_vector_type(8)));
typedef _Float16 f16x4 __attribute__((ext_vector_type(4)));

// ---------------- LDS byte map (regions alias across phases) ----------------
// phase A: XP  @0..25872      x staged f16 [49][264ch] stride 528 (dies after conv0)
//          XF  @63936..76872  conv0 out [49][132] stride 264 (dies after conv1)
//          XF2 @0..12936      conv1 out (x_feat), aliases XP
//          ST  @12960..63920  static gates f32 [49 pix][stride 1040B]
// phase B: PL  @0..12936      planes [49][132]: h0 ch0..63 (byte 0..127), h1 (128..255)
//          ST persists; FCP fc partials @76896; PRD 2 ints @77920
// Z512 @77952: zeros, never written after init — OOW fallback for B loads
#define XP    0
#define XF    63936
#define XF2   0
#define PL    0
#define ST    12960
#define STSTR 1040
#define FCP   76896
#define PRD   77920
#define Z512  77952
#define LDSB  78464

__device__ __forceinline__ float sigmoidf_(float v) { return 1.0f / (1.0f + expf(-v)); }

// shifted-window conv GEMM, weights hi/lo f16 (A), acts single f16 (B):
// acc += Al*B + Ah*B. Tap loop deliberately NOT unrolled: keeps the
// scheduling window small so the allocator doesn't hoist 9 taps' worth of
// loads and spill acc to scratch (round-5/6 failure mode: 6.5 GB scratch).
template <int NKC, int NMI>
__device__ __forceinline__ void conv_mfma_run(
    const char* __restrict__ SHb, int baseB, int pstr2,
    const int (&kofs)[NKC], int q16,
    const _Float16* __restrict__ ghi, const _Float16* __restrict__ glo,
    int NMF, int miBase, int miStep,
    const int (&okc)[4], const int (&py0)[4], const int (&px0)[4],
    f32x4 (&acc)[NMI][4], int lane)
{
    #pragma unroll 1
    for (int tap = 0; tap < 9; ++tap) {
        const int dy = tap / 3 - 1, dx = tap % 3 - 1;
        int bb[4];
        #pragma unroll
        for (int n = 0; n < 4; ++n) {
            int py = py0[n] + dy, px = px0[n] + dx;
            bool ok = okc[n] && ((unsigned)py < 7u) && ((unsigned)px < 7u);
            bb[n] = ok ? baseB + (py * 7 + px) * pstr2 : Z512;  // Z512+kof<=Z512+496: zeros
        }
        #pragma unroll
        for (int kc = 0; kc < NKC; ++kc) {
            const int kof = kofs[kc] + q16;
            f16x8 B[4];
            #pragma unroll
            for (int n = 0; n < 4; ++n) B[n] = *(const f16x8*)(SHb + bb[n] + kof);
            #pragma unroll
            for (int ii = 0; ii < NMI; ++ii) {
                int frag = (((tap * NKC + kc) * NMF + (miBase + ii * miStep)) << 9) + lane * 8;
                f16x8 Ah = *(const f16x8*)(ghi + frag);
                f16x8 Al = *(const f16x8*)(glo + frag);
                #pragma unroll
                for (int n = 0; n < 4; ++n) {
                    acc[ii][n] = __builtin_amdgcn_mfma_f32_16x16x32_f16(Al, B[n], acc[ii][n], 0, 0, 0);
                    acc[ii][n] = __builtin_amdgcn_mfma_f32_16x16x32_f16(Ah, B[n], acc[ii][n], 0, 0, 0);
                }
            }
        }
    }
}

// one-hot map conv contribution injected at acc-init (map one-hot at pixel pv)
__device__ __forceinline__ void inject_onehot(
    f32x4 (&acc)[4][4], const float* __restrict__ wv, int pv,
    const int (&okc)[4], const int (&py0)[4], const int (&px0)[4], int w, int q)
{
    if (pv >= 49) return;                 // EOS / empty map
    int vy = pv / 7, vx = pv % 7;
    #pragma unroll
    for (int n = 0; n < 4; ++n) {
        int dy = vy - py0[n], dx = vx - px0[n];
        if (okc[n] && dy >= -1 && dy <= 1 && dx >= -1 && dx <= 1) {
            int tap = (dy + 1) * 3 + (dx + 1);
            const float* wp = wv + tap * 256 + w * 16 + q * 4;
            #pragma unroll
            for (int g = 0; g < 4; ++g)
                acc[g][n] += *(const f32x4*)(wp + g * 64);
        }
    }
}

extern "C" __global__ __launch_bounds__(256, 2)
void poly_fused(const float* __restrict__ x, const int* __restrict__ firstv,
                const float* __restrict__ b_c0, const float* __restrict__ b_c1,
                const float* __restrict__ cx0b, const float* __restrict__ ch0b,
                const float* __restrict__ cx1b, const float* __restrict__ ch1b,
                const float* __restrict__ fcb,
                const _Float16* __restrict__ c0hi, const _Float16* __restrict__ c0lo,
                const _Float16* __restrict__ c1hi, const _Float16* __restrict__ c1lo,
                const _Float16* __restrict__ cshi, const _Float16* __restrict__ cslo,
                const _Float16* __restrict__ g0hi, const _Float16* __restrict__ g0lo,
                const _Float16* __restrict__ g1hi, const _Float16* __restrict__ g1lo,
                const _Float16* __restrict__ fchi, const _Float16* __restrict__ fclo,
                const float* __restrict__ wv1,
                const float* __restrict__ wvp1, const float* __restrict__ wvp2,
                float* __restrict__ out)
{
    extern __shared__ char SHC[];
    float* SHf = (float*)SHC;
    const int tid = threadIdx.x, s = blockIdx.x;
    const int lane = tid & 63, w = tid >> 6;
    const int q = lane >> 4, l15 = lane & 15, q16 = q * 16;

    for (int i = tid; i < LDSB / 4; i += 256) SHf[i] = 0.f;
    __syncthreads();

    // per-lane column geometry (col = n*16 + l15; 49 live pixels)
    int okc[4], py0[4], px0[4];
    #pragma unroll
    for (int n = 0; n < 4; ++n) {
        int col = n * 16 + l15;
        okc[n] = col < 49;
        int p = okc[n] ? col : 0;
        py0[n] = p / 7; px0[n] = p % 7;
    }

    // ============ PHASE A ============
    const float* xs = x + (size_t)s * 12544;
    for (int e = tid; e < 12544; e += 256) {
        int ch = e / 49, p = e - ch * 49;
        *(_Float16*)(SHC + XP + p * 528 + ch * 2) = (_Float16)xs[e];
    }
    __syncthreads();                       // XP visible

    const int kofs8[8] = {0, 64, 128, 192, 256, 320, 384, 448};
    const int kofs4[4] = {0, 64, 128, 192};
    const int kofs2[2] = {0, 64};

    // conv0: M=128 (8 mfrags; wave owns w*2, w*2+1), K=256
    {
        f32x4 acc2[2][4];
        #pragma unroll
        for (int ii = 0; ii < 2; ++ii)
            #pragma unroll
            for (int n = 0; n < 4; ++n) acc2[ii][n] = (f32x4){0.f, 0.f, 0.f, 0.f};
        conv_mfma_run<8, 2>(SHC, XP, 528, kofs8, q16, c0hi, c0lo,
                            8, w * 2, 1, okc, py0, px0, acc2, lane);
        #pragma unroll
        for (int ii = 0; ii < 2; ++ii) {
            f32x4 bb = *(const f32x4*)(b_c0 + (w * 2 + ii) * 16 + q * 4);
            int chB = ((w * 2 + ii) * 16 + q * 4) * 2;
            #pragma unroll
            for (int n = 0; n < 4; ++n) if (okc[n]) {
                int p = n * 16 + l15;
                f16x4 h;
                #pragma unroll
                for (int r = 0; r < 4; ++r)
                    h[r] = (_Float16)fmaxf(acc2[ii][n][r] + bb[r], 0.f);
                *(f16x4*)(SHC + XF + p * 264 + chB) = h;
            }
        }
    }
    __syncthreads();                       // XF visible; XP dead

    // conv1: M=128, K=128, XF -> XF2 (aliases XP)
    {
        f32x4 acc2[2][4];
        #pragma unroll
        for (int ii = 0; ii < 2; ++ii)
            #pragma unroll
            for (int n = 0; n < 4; ++n) acc2[ii][n] = (f32x4){0.f, 0.f, 0.f, 0.f};
        conv_mfma_run<4, 2>(SHC, XF, 264, kofs4, q16, c1hi, c1lo,
                            8, w * 2, 1, okc, py0, px0, acc2, lane);
        #pragma unroll
        for (int ii = 0; ii < 2; ++ii) {
            f32x4 bb = *(const f32x4*)(b_c1 + (w * 2 + ii) * 16 + q * 4);
            int chB = ((w * 2 + ii) * 16 + q * 4) * 2;
            #pragma unroll
            for (int n = 0; n < 4; ++n) if (okc[n]) {
                int p = n * 16 + l15;
                f16x4 h;
                #pragma unroll
                for (int r = 0; r < 4; ++r)
                    h[r] = (_Float16)fmaxf(acc2[ii][n][r] + bb[r], 0.f);
                *(f16x4*)(SHC + XF2 + p * 264 + chB) = h;
            }
        }
    }
    __syncthreads();                       // XF2 visible; XF dead

    // static gates -> ST in LDS: st = conv_cs(x_feat) + (cx0b+ch0b) + v_first window
    const int fv = firstv[s];
    {
        f32x4 acc[4][4];
        #pragma unroll
        for (int g = 0; g < 4; ++g)
            #pragma unroll
            for (int n = 0; n < 4; ++n) acc[g][n] = (f32x4){0.f, 0.f, 0.f, 0.f};
        conv_mfma_run<4, 4>(SHC, XF2, 264, kofs4, q16, cshi, cslo,
                            16, w, 4, okc, py0, px0, acc, lane);
        const int fy = fv / 7, fx = fv % 7;
        #pragma unroll
        for (int g = 0; g < 4; ++g) {
            int m0 = g * 64 + w * 16 + q * 4;
            f32x4 b0 = *(const f32x4*)(cx0b + m0);
            f32x4 bh = *(const f32x4*)(ch0b + m0);
            #pragma unroll
            for (int n = 0; n < 4; ++n) {
                f32x4 v = acc[g][n] + b0 + bh;
                int dy = fy - py0[n], dx = fx - px0[n];
                if (okc[n] && dy >= -1 && dy <= 1 && dx >= -1 && dx <= 1) {
                    int tap = (dy + 1) * 3 + (dx + 1);
                    v += *(const f32x4*)(wv1 + tap * 256 + m0);
                }
                if (okc[n]) {
                    int p = n * 16 + l15;
                    *(f32x4*)(SHC + ST + p * STSTR + m0 * 4) = v;
                }
            }
        }
    }
    __syncthreads();                       // ST visible; XF2 dead

    // zero PL (aliases XF2) + init preds: vp1 = v_first, vp2 = empty(49)
    for (int i = tid; i < 12936 / 4; i += 256) SHf[i] = 0.f;
    if (tid == 0) { ((int*)(SHC + PRD))[0] = fv; ((int*)(SHC + PRD))[1] = 49; }
    __syncthreads();

    // layer-1 biases cached in registers
    f32x4 b1[4];
    #pragma unroll
    for (int g = 0; g < 4; ++g) {
        int m0 = g * 64 + w * 16 + q * 4;
        b1[g] = *(const f32x4*)(cx1b + m0) + *(const f32x4*)(ch1b + m0);
    }

    float c0s[4][4], c1s[4][4];
    #pragma unroll
    for (int n = 0; n < 4; ++n)
        #pragma unroll
        for (int r = 0; r < 4; ++r) { c0s[n][r] = 0.f; c1s[n][r] = 0.f; }

    float* outS = out + (size_t)s * 450;

    // ============ PHASE B: 9 recurrent steps ============
    for (int t = 0; t < 9; ++t) {
        f32x4 acc[4][4];
        // ---- L0 gates: acc = ST + vp1/vp2 injections; conv over h0 (K=64) ----
        #pragma unroll
        for (int g = 0; g < 4; ++g) {
            int m0 = g * 64 + w * 16 + q * 4;
            #pragma unroll
            for (int n = 0; n < 4; ++n) {
                int p = okc[n] ? (n * 16 + l15) : 0;
                acc[g][n] = *(const f32x4*)(SHC + ST + p * STSTR + m0 * 4);
            }
        }
        {
            int p1 = ((const int*)(SHC + PRD))[0];
            int p2 = ((const int*)(SHC + PRD))[1];
            inject_onehot(acc, wvp1, p1, okc, py0, px0, w, q);
            inject_onehot(acc, wvp2, p2, okc, py0, px0, w, q);
        }
        conv_mfma_run<2, 4>(SHC, PL, 264, kofs2, q16, g0hi, g0lo,
                            16, w, 4, okc, py0, px0, acc, lane);
        __syncthreads();                   // L0 reads of h0 done
        {   // L0 LSTM epilogue (in-lane), write h0 f16
            int chB = (w * 16 + q * 4) * 2;
            #pragma unroll
            for (int n = 0; n < 4; ++n) if (okc[n]) {
                int p = n * 16 + l15;
                f16x4 h;
                #pragma unroll
                for (int r = 0; r < 4; ++r) {
                    float ig = sigmoidf_(acc[0][n][r]);
                    float fg = sigmoidf_(acc[1][n][r]);
                    float gg = tanhf(acc[2][n][r]);
                    float og = sigmoidf_(acc[3][n][r]);
                    float cy = fg * c0s[n][r] + ig * gg;
                    c0s[n][r] = cy;
                    h[r] = (_Float16)(og * tanhf(cy));
                }
                *(f16x4*)(SHC + PL + p * 264 + chB) = h;
            }
        }
        __syncthreads();                   // h0 visible
        // ---- L1 gates: K = [h0 new | h1 old] = PL ch 0..127 ----
        #pragma unroll
        for (int g = 0; g < 4; ++g)
            #pragma unroll
            for (int n = 0; n < 4; ++n) acc[g][n] = b1[g];
        conv_mfma_run<4, 4>(SHC, PL, 264, kofs4, q16, g1hi, g1lo,
                            16, w, 4, okc, py0, px0, acc, lane);
        __syncthreads();                   // L1 reads of h1-old done
        {   // L1 LSTM epilogue, write h1 f16
            int chB = 128 + (w * 16 + q * 4) * 2;
            #pragma unroll
            for (int n = 0; n < 4; ++n) if (okc[n]) {
                int p = n * 16 + l15;
                f16x4 h;
                #pragma unroll
                for (int r = 0; r < 4; ++r) {
                    float ig = sigmoidf_(acc[0][n][r]);
                    float fg = sigmoidf_(acc[1][n][r]);
                    float gg = tanhf(acc[2][n][r]);
                    float og = sigmoidf_(acc[3][n][r]);
                    float cy = fg * c1s[n][r] + ig * gg;
                    c1s[n][r] = cy;
                    h[r] = (_Float16)(og * tanhf(cy));
                }
                *(f16x4*)(SHC + PL + p * 264 + chB) = h;
            }
        }
        __syncthreads();                   // h1 visible (fc input)
        {   // fc via MFMA: M=64 (50 live), K=3136 from PL h1; col 0 live
            f32x4 afc[4];
            #pragma unroll
            for (int mi = 0; mi < 4; ++mi) afc[mi] = (f32x4){0.f, 0.f, 0.f, 0.f};
            int kc0 = w * 25;
            int kcN = (w < 3) ? 25 : 23;
            #pragma unroll 1
            for (int kc = 0; kc < kcN; ++kc) {
                int kg = kc0 + kc;
                int aB = (l15 == 0) ? (PL + (kg >> 1) * 264 + 128 + (kg & 1) * 64 + q16) : Z512;
                f16x8 B = *(const f16x8*)(SHC + aB);
                #pragma unroll
                for (int mi = 0; mi < 4; ++mi) {
                    int frag = ((kg * 4 + mi) << 9) + lane * 8;
                    f16x8 Ah = *(const f16x8*)(fchi + frag);
                    f16x8 Al = *(const f16x8*)(fclo + frag);
                    afc[mi] = __builtin_amdgcn_mfma_f32_16x16x32_f16(Al, B, afc[mi], 0, 0, 0);
                    afc[mi] = __builtin_amdgcn_mfma_f32_16x16x32_f16(Ah, B, afc[mi], 0, 0, 0);
                }
            }
            if (l15 == 0) {
                #pragma unroll
                for (int mi = 0; mi < 4; ++mi)
                    *(f32x4*)(SHC + FCP + w * 256 + mi * 64 + q16) = afc[mi];
            }
        }
        __syncthreads();                   // fc partials visible
        if (tid < 64) {
            int c = tid;
            const float* fp = (const float*)(SHC + FCP);
            float lg = fp[c] + fp[64 + c] + fp[128 + c] + fp[192 + c];
            float v = -3.4e38f;
            if (c < 50) { lg += fcb[c]; outS[t * 50 + c] = lg; v = lg; }
            int idx = c;
            #pragma unroll
            for (int off = 1; off < 64; off <<= 1) {
                float ov = __shfl_xor(v, off, 64);
                int   oi = __shfl_xor(idx, off, 64);
                if (ov > v || (ov == v && oi < idx)) { v = ov; idx = oi; }
            }
            if (c == 0) {
                int* pr = (int*)(SHC + PRD);
                pr[1] = pr[0];             // vp2 <- vp1
                pr[0] = idx;               // vp1 <- one-hot(pred)
            }
        }
        __syncthreads();                   // PRD visible; FCP reusable
    }
}

// ================= weight repack kernels =================
// OIHW conv weights -> A fragments [tap][kc][mi][lane][8], hi/lo f16 split
__global__ void repack_frags_k(const float* __restrict__ w, _Float16* __restrict__ ohi,
                               _Float16* __restrict__ olo, int ICS, int KMAX,
                               int NKC, int NMF, int total) {
    int i = blockIdx.x * 256 + threadIdx.x;
    if (i >= total) return;
    int j = i & 7, lane = (i >> 3) & 63;
    int rest = i >> 9;
    int mi = rest % NMF; rest /= NMF;
    int kc = rest % NKC; int tap = rest / NKC;
    int m = mi * 16 + (lane & 15);
    int k = kc * 32 + ((lane >> 4) & 3) * 8 + j;
    float v = (k < KMAX) ? w[((size_t)m * ICS + k) * 9 + tap] : 0.f;
    _Float16 hv = (_Float16)v;
    ohi[i] = hv; olo[i] = (_Float16)(v - (float)hv);
}

__global__ void repack_g1_k(const float* __restrict__ cx1w, const float* __restrict__ ch1w,
                            _Float16* __restrict__ ohi, _Float16* __restrict__ olo) {
    int i = blockIdx.x * 256 + threadIdx.x;
    if (i >= 294912) return;
    int j = i & 7; int lane = (i >> 3) & 63; int mt = (i >> 9) & 15;
    int rest = i >> 13; int kc = rest & 3; int tap = rest >> 2;
    int m = mt * 16 + (lane & 15);
    int kk = (lane >> 4) * 8 + j;
    float wv;
    if (kc < 2) wv = cx1w[((size_t)m * 64 + kc * 32 + kk) * 9 + tap];
    else        wv = ch1w[((size_t)m * 64 + (kc - 2) * 32 + kk) * 9 + tap];
    _Float16 hv = (_Float16)wv;
    ohi[i] = hv; olo[i] = (_Float16)(wv - (float)hv);
}

// fc weights [50][3136] -> frags [kc 98][mi 4][lane][8], k = p*64+ch
__global__ void repack_fc_k(const float* __restrict__ fcw, _Float16* __restrict__ ohi,
                            _Float16* __restrict__ olo) {
    int i = blockIdx.x * 256 + threadIdx.x;
    if (i >= 200704) return;
    int j = i & 7, lane = (i >> 3) & 63;
    int rest = i >> 9;
    int mi = rest & 3, kc = rest >> 2;
    int cls = mi * 16 + (lane & 15);
    int k = kc * 32 + ((lane >> 4) & 3) * 8 + j;
    int ch = k & 63, p = k >> 6;
    float v = (cls < 50) ? fcw[(size_t)cls * 3136 + ch * 49 + p] : 0.f;
    _Float16 hv = (_Float16)v;
    ohi[i] = hv; olo[i] = (_Float16)(v - (float)hv);
}

// one-hot conv tables: wv[tap][m] = cx0w[m, ic, tap]
__global__ void repack_wv_k(const float* __restrict__ cx0w, float* __restrict__ o, int ic) {
    int i = blockIdx.x * 256 + threadIdx.x;
    if (i >= 2304) return;
    int tap = i / 256, m = i % 256;
    o[i] = cx0w[((size_t)m * 131 + ic) * 9 + tap];
}

extern "C" void kernel_launch(void* const* d_in, const int* in_sizes, int n_in,
                              void* d_out, int out_size, void* d_ws, size_t ws_size,
                              hipStream_t stream)
{
    const float* x     = (const float*)d_in[0];
    const int*   fv    = (const int*)  d_in[1];
    const float* c0w   = (const float*)d_in[2];
    const float* c0b   = (const float*)d_in[3];
    const float* c1w   = (const float*)d_in[4];
    const float* c1b   = (const float*)d_in[5];
    const float* cx0w  = (const float*)d_in[6];
    const float* cx0b  = (const float*)d_in[7];
    const float* ch0w  = (const float*)d_in[8];
    const float* ch0b  = (const float*)d_in[9];
    const float* cx1w  = (const float*)d_in[10];
    const float* cx1b  = (const float*)d_in[11];
    const float* ch1w  = (const float*)d_in[12];
    const float* ch1b  = (const float*)d_in[13];
    const float* fcw   = (const float*)d_in[14];
    const float* fcb   = (const float*)d_in[15];
    float* out = (float*)d_out;
    const int n = in_sizes[0] / 12544;

    _Float16* h = (_Float16*)d_ws;
    _Float16* g0hi = h;                  // 147456 (NKC=2, NMF=16)
    _Float16* g0lo = g0hi + 147456;
    _Float16* g1hi = g0lo + 147456;      // 294912
    _Float16* g1lo = g1hi + 294912;
    _Float16* c0hi = g1lo + 294912;      // 294912
    _Float16* c0lo = c0hi + 294912;
    _Float16* c1hi = c0lo + 294912;      // 147456
    _Float16* c1lo = c1hi + 147456;
    _Float16* cshi = c1lo + 147456;      // 294912
    _Float16* cslo = cshi + 294912;
    _Float16* fchi = cslo + 294912;      // 200704
    _Float16* fclo = fchi + 200704;
    float*    wv1  = (float*)(fclo + 200704);   // 2304 f32 each
    float*    wvp1 = wv1 + 2304;
    float*    wvp2 = wvp1 + 2304;

    repack_frags_k<<<(147456 + 255) / 256, 256, 0, stream>>>(ch0w, g0hi, g0lo, 64, 64, 2, 16, 147456);
    repack_g1_k   <<<(294912 + 255) / 256, 256, 0, stream>>>(cx1w, ch1w, g1hi, g1lo);
    repack_frags_k<<<(294912 + 255) / 256, 256, 0, stream>>>(c0w, c0hi, c0lo, 256, 256, 8, 8, 294912);
    repack_frags_k<<<(147456 + 255) / 256, 256, 0, stream>>>(c1w, c1hi, c1lo, 128, 128, 4, 8, 147456);
    repack_frags_k<<<(294912 + 255) / 256, 256, 0, stream>>>(cx0w, cshi, cslo, 131, 128, 4, 16, 294912);
    repack_fc_k   <<<(200704 + 255) / 256, 256, 0, stream>>>(fcw, fchi, fclo);
    repack_wv_k   <<<(2304 + 255) / 256, 256, 0, stream>>>(cx0w, wv1, 130);
    repack_wv_k   <<<(2304 + 255) / 256, 256, 0, stream>>>(cx0w, wvp1, 129);
    repack_wv_k   <<<(2304 + 255) / 256, 256, 0, stream>>>(cx0w, wvp2, 128);

    (void)hipFuncSetAttribute((const void*)poly_fused,
                              hipFuncAttributeMaxDynamicSharedMemorySize, LDSB);
    poly_fused<<<n, 256, LDSB, stream>>>(x, fv, c0b, c1b, cx0b, ch0b, cx1b, ch1b, fcb,
                                         c0hi, c0lo, c1hi, c1lo, cshi, cslo,
                                         g0hi, g0lo, g1hi, g1lo, fchi, fclo,
                                         wv1, wvp1, wvp2, out);
}